// Round 22
// baseline (618.584 us; speedup 1.0000x reference)
//
#include <hip/hip_runtime.h>
#include <hip/hip_bf16.h>
#include <stdint.h>

#define Bq  8
#define Sq  2048
#define Dq  768
#define Hq  3072
#define Oq  768
#define Eq  8
#define Mq  (Bq*Sq)            // 16384 tokens
#define LN_EPS 1e-5f
#define MAX_T256 (Mq/128 + 16)      // 144 worst-case padded 256-row tiles
#define NB_ROUTER (Mq/4)            // 4096 router blocks (1 token/wave)
#define NB_TRANS  (2*Eq*576)        // 9216 transpose blocks (64x64 tiles)

typedef unsigned short u16;
typedef __attribute__((ext_vector_type(4))) float f32x4;
typedef __attribute__((ext_vector_type(8))) __bf16 bf16x8;

static __device__ __forceinline__ u16 f2bf(float f) {
  __hip_bfloat16 h = __float2bfloat16(f);
  return __builtin_bit_cast(u16, h);
}
static __device__ __forceinline__ float bf2f(u16 h) {
  uint32_t u = (uint32_t)h << 16;
  return __builtin_bit_cast(float, u);
}

static __device__ __forceinline__ float gelu_f(float x) {
  float u = 0.7978845608028654f * x * (1.0f + 0.044715f * x * x);
  float e = __expf(2.0f * u);
  float t = 1.0f - 2.0f / (e + 1.0f);   // tanh(u), NaN-free
  return 0.5f * x * (1.0f + t);
}

typedef const __attribute__((address_space(1))) void* gas_t;
typedef __attribute__((address_space(3))) void* las_t;
static __device__ __forceinline__ void gload16(const void* g, void* l) {
  __builtin_amdgcn_global_load_lds((gas_t)g, (las_t)l, 16, 0, 0);
}

// ---------------- UNION prep kernel: router+cvt (1 token/wave) and weight
// transpose blocks in ONE dispatch so the two streams overlap.
// blockIdx.x < NB_ROUTER: router path (4 tokens/block, 24KB rw^T LDS).
// else: 64x64 transpose+cvt tile of w1 (which=0) or w2 (which=1).
__global__ __launch_bounds__(256) void prep_kernel(
    const float* __restrict__ x, const float* __restrict__ rw,
    const float* __restrict__ rb, u16* __restrict__ Xbf,
    int* __restrict__ tok_seg, float2* __restrict__ tok_w,
    int* __restrict__ cnt,
    const float* __restrict__ w1, u16* __restrict__ W1T,
    const float* __restrict__ w2, u16* __restrict__ W2T)
{
  __shared__ float smem_u[6144];        // 24KB: rwT (router) / 64x65 tile
  const int bid = (int)blockIdx.x;

  if (bid < NB_ROUTER) {
    // ------------- router + x->bf16 path: one token per wave
    if (bid == 0 && threadIdx.x < 16) cnt[threadIdx.x] = 0;
    float* rwT = smem_u;
    for (int i = threadIdx.x; i < Eq * Dq; i += 256)
      rwT[(i & 7) * Dq + (i >> 3)] = rw[i];
    __syncthreads();

    int wid = threadIdx.x >> 6;
    int lane = threadIdx.x & 63;
    int token = bid * 4 + wid;
    const float4* xrow = (const float4*)(x + (size_t)token * Dq);
    ushort4* orow = (ushort4*)(Xbf + (size_t)token * Dq);

    float acc[Eq];
#pragma unroll
    for (int e = 0; e < Eq; e++) acc[e] = 0.f;

#pragma unroll
    for (int it = 0; it < Dq / 256; it++) {
      int d4 = it * 64 + lane;
      float4 xv = xrow[d4];
      ushort4 o;
      o.x = f2bf(xv.x); o.y = f2bf(xv.y); o.z = f2bf(xv.z); o.w = f2bf(xv.w);
      orow[d4] = o;
      int d = d4 * 4;
#pragma unroll
      for (int e = 0; e < Eq; e++) {
        float4 wv = *(const float4*)&rwT[e * Dq + d];
        acc[e] += xv.x * wv.x + xv.y * wv.y + xv.z * wv.z + xv.w * wv.w;
      }
    }
#pragma unroll
    for (int e = 0; e < Eq; e++) {
      float v = acc[e];
#pragma unroll
      for (int off = 32; off; off >>= 1) v += __shfl_xor(v, off);
      acc[e] = v;
    }
    if (lane == 0) {
      float v1 = -1e30f, v2 = -1e30f; int i1 = 0, i2 = 0;
#pragma unroll
      for (int e = 0; e < Eq; e++) {
        float v = acc[e] + rb[e];
        if (v > v1)      { v2 = v1; i2 = i1; v1 = v; i1 = e; }
        else if (v > v2) { v2 = v;  i2 = e; }
      }
      float ex = expf(v2 - v1);
      float wa = 1.f / (1.f + ex);
      float wb = ex / (1.f + ex);
      tok_seg[token] = i1 | ((8 + i2) << 8);
      tok_w[token] = make_float2(wa, wb);
    }
  } else {
    // ------------- 64x64 transpose+cvt path
    const int idx = bid - NB_ROUTER;
    const int which = idx / (Eq * 576);
    const int rem = idx % (Eq * 576);
    const int ex = rem / 576;
    const int tidx = rem % 576;
    const int R = which ? Hq : Dq;
    const int C = which ? Oq : Hq;
    const int NC = C / 64;
    const float* in = (which ? w2 : w1) + (size_t)ex * R * C;
    u16* out = (which ? W2T : W1T) + (size_t)ex * R * C;
    const int c0 = (tidx % NC) * 64;
    const int r0 = (tidx / NC) * 64;
#define TILE(rr, cc) smem_u[(rr) * 65 + (cc)]
    const int fx = threadIdx.x & 15, rbk = threadIdx.x >> 4;   // rbk 0..15
#pragma unroll
    for (int rr = 0; rr < 64; rr += 16) {
      float4 v = *(const float4*)&in[(size_t)(r0 + rr + rbk) * C + c0 + fx * 4];
      TILE(rr + rbk, fx * 4 + 0) = v.x;
      TILE(rr + rbk, fx * 4 + 1) = v.y;
      TILE(rr + rbk, fx * 4 + 2) = v.z;
      TILE(rr + rbk, fx * 4 + 3) = v.w;
    }
    __syncthreads();
    const int j = threadIdx.x & 7;        // 8 lanes per out-row
#pragma unroll
    for (int pass = 0; pass < 2; ++pass) {
      int oc = (threadIdx.x >> 3) + pass * 32;
      u16 vals[8];
#pragma unroll
      for (int k = 0; k < 8; ++k) vals[k] = f2bf(TILE(j * 8 + k, oc));
      uint4 w;
      w.x = vals[0] | ((uint32_t)vals[1] << 16);
      w.y = vals[2] | ((uint32_t)vals[3] << 16);
      w.z = vals[4] | ((uint32_t)vals[5] << 16);
      w.w = vals[6] | ((uint32_t)vals[7] << 16);
      *(uint4*)&out[(size_t)(c0 + oc) * R + r0 + j * 8] = w;
    }
#undef TILE
  }
}

// ---------------- segment-list build, block-aggregated atomics.
// Also records each token's (seg,pos) handle pair for the combine-LN.
__global__ __launch_bounds__(256) void scatter_build(
    const int* __restrict__ tok_seg, const float2* __restrict__ tok_w,
    int* __restrict__ cnt, int* __restrict__ seg_tok, float* __restrict__ seg_wgt,
    int2* __restrict__ tok_pos)
{
  __shared__ int histA[16], histB[16], base[16];
  int t = threadIdx.x;
  if (t < 16) { histA[t] = 0; histB[t] = 0; }
  __syncthreads();
  int token = blockIdx.x * 256 + t;
  int sp = tok_seg[token];
  float2 wv = tok_w[token];
  int s0 = sp & 0xff, s1 = sp >> 8;
  atomicAdd(&histA[s0], 1);
  atomicAdd(&histA[s1], 1);
  __syncthreads();
  if (t < 16) base[t] = atomicAdd(&cnt[t], histA[t]);
  __syncthreads();
  int p0 = base[s0] + atomicAdd(&histB[s0], 1);
  seg_tok[(size_t)s0 * Mq + p0] = token;
  seg_wgt[(size_t)s0 * Mq + p0] = wv.x;
  int p1 = base[s1] + atomicAdd(&histB[s1], 1);
  seg_tok[(size_t)s1 * Mq + p1] = token;
  seg_wgt[(size_t)s1 * Mq + p1] = wv.y;
  tok_pos[token] = make_int2(s0 | (p0 << 4), s1 | (p1 << 4));
}

// ---------------- GEMM1: 256x256 tile, 8 waves (2Mx4N), BK=64, phase-
// pipelined K-loop; LDS 128KB flat smem; coalesced LDS-staged epilogue
// (out-tile XOR-swizzled to kill ds_write bank conflicts).
__global__ __launch_bounds__(512, 2) void moe_gemm1(
    const u16* __restrict__ A, const u16* __restrict__ W,
    const float* __restrict__ bias, u16* __restrict__ Hout,
    const int* __restrict__ cnt, const int* __restrict__ seg_tok,
    int K, int N, int tile_lo)
{
  const int NP = N / 256;               // 12 panels
  const int lid = (int)blockIdx.x + NP * (int)blockIdx.y;
  const int xcd = lid & 7, slot = lid >> 3;
  const int t_loc = xcd + 8 * (slot / NP);   // gridDim.y multiple of 8
  const int panel = slot % NP;

  const int t = tile_lo + t_loc;
  int pfx[16];
  {
    int tot = 0;
#pragma unroll
    for (int s2 = 0; s2 < 16; s2++) { pfx[s2] = tot; tot += (cnt[s2] + 255) >> 8; }
    if (t >= tot) return;
  }
  int seg = 0;
#pragma unroll
  for (int s2 = 1; s2 < 16; s2++) if (pfx[s2] <= t) seg = s2;
  const int e = seg & 7;
  const int segcnt = cnt[seg];
  const int ti = t - pfx[seg];
  const int lt = t_loc;

  __shared__ u16 smem[65536];           // 128 KB
  const int tid  = threadIdx.x;
  const int lane = tid & 63;
  const int wid  = tid >> 6;
  const int wr   = wid >> 2, wc = wid & 3;    // 2M x 4N waves
  const int lrow = lane & 15, kgrp = lane >> 4;
  const int gcx0 = ((kgrp)     ^ (lrow & 7)) * 8;
  const int gcx1 = ((4 + kgrp) ^ (lrow & 7)) * 8;

  f32x4 acc[8][4];
#pragma unroll
  for (int m = 0; m < 8; m++)
#pragma unroll
    for (int n = 0; n < 4; n++) acc[m][n] = (f32x4){0.f, 0.f, 0.f, 0.f};

  const int srow = tid >> 3;
  const int swz  = ((tid & 7) ^ (srow & 7)) * 8;
  const u16 *pA00, *pA01, *pA10, *pA11, *pB00, *pB01, *pB10, *pB11;
  {
    int sr;
    sr = ti * 256 +   0 +  0 + srow;
    pA00 = A + (size_t)((sr < segcnt) ? seg_tok[(size_t)seg * Mq + sr] : 0) * K + swz;
    sr = ti * 256 +   0 + 64 + srow;
    pA01 = A + (size_t)((sr < segcnt) ? seg_tok[(size_t)seg * Mq + sr] : 0) * K + swz;
    sr = ti * 256 + 128 +  0 + srow;
    pA10 = A + (size_t)((sr < segcnt) ? seg_tok[(size_t)seg * Mq + sr] : 0) * K + swz;
    sr = ti * 256 + 128 + 64 + srow;
    pA11 = A + (size_t)((sr < segcnt) ? seg_tok[(size_t)seg * Mq + sr] : 0) * K + swz;
    const u16* Wb = W + (size_t)e * K * N;
    pB00 = Wb + (size_t)(panel * 256 +   0 +  0 + srow) * K + swz;
    pB01 = Wb + (size_t)(panel * 256 +   0 + 64 + srow) * K + swz;
    pB10 = Wb + (size_t)(panel * 256 + 128 +  0 + srow) * K + swz;
    pB11 = Wb + (size_t)(panel * 256 + 128 + 64 + srow) * K + swz;
  }

#define STG(base, h, P0, P1)                               \
  do {                                                     \
    gload16(P0, &smem[(base) + (h) * 8192 + tid * 8]);     \
    gload16(P1, &smem[(base) + (h) * 8192 + 4096 + tid * 8]); \
    P0 += 64; P1 += 64;                                    \
  } while (0)

  const int NKT = K / 64;               // 12 K-tiles
  STG(0, 0, pA00, pA01); STG(0, 1, pA10, pA11);
  STG(32768, 0, pB00, pB01); STG(32768, 1, pB10, pB11);

  bf16x8 bfr[4][2];
  for (int kt = 0; kt < NKT; ++kt) {
    const int s = kt & 1;
    const int sA = s * 16384, sB = 32768 + s * 16384;
    const int dA = (s ^ 1) * 16384, dB = 32768 + (s ^ 1) * 16384;
    const bool more = (kt + 1 < NKT);
    const int abase = wr * 128 + lrow;
    const int bbase = wc * 64 + lrow;

    // ---- phase 0
    if (more) {
      STG(dA, 0, pA00, pA01);
      asm volatile("s_waitcnt vmcnt(2)" ::: "memory");
    } else {
      asm volatile("s_waitcnt vmcnt(0)" ::: "memory");
    }
    __builtin_amdgcn_s_barrier();
    __builtin_amdgcn_sched_barrier(0);
#pragma unroll
    for (int n = 0; n < 4; n++) {
      bfr[n][0] = *(const bf16x8*)&smem[sB + (bbase + n * 16) * 64 + gcx0];
      bfr[n][1] = *(const bf16x8*)&smem[sB + (bbase + n * 16) * 64 + gcx1];
    }
    {
      bf16x8 a00 = *(const bf16x8*)&smem[sA + (abase +  0) * 64 + gcx0];
      bf16x8 a01 = *(const bf16x8*)&smem[sA + (abase +  0) * 64 + gcx1];
      bf16x8 a10 = *(const bf16x8*)&smem[sA + (abase + 16) * 64 + gcx0];
      bf16x8 a11 = *(const bf16x8*)&smem[sA + (abase + 16) * 64 + gcx1];
      __builtin_amdgcn_s_setprio(1);
#pragma unroll
      for (int n = 0; n < 4; n++) {
        acc[0][n] = __builtin_amdgcn_mfma_f32_16x16x32_bf16(a00, bfr[n][0], acc[0][n], 0, 0, 0);
        acc[0][n] = __builtin_amdgcn_mfma_f32_16x16x32_bf16(a01, bfr[n][1], acc[0][n], 0, 0, 0);
        acc[1][n] = __builtin_amdgcn_mfma_f32_16x16x32_bf16(a10, bfr[n][0], acc[1][n], 0, 0, 0);
        acc[1][n] = __builtin_amdgcn_mfma_f32_16x16x32_bf16(a11, bfr[n][1], acc[1][n], 0, 0, 0);
      }
      __builtin_amdgcn_s_setprio(0);
    }
    __builtin_amdgcn_sched_barrier(0);
    __builtin_amdgcn_s_barrier();

#define PHASE(q, STGSTMT)                                                     \
    do {                                                                      \
      bf16x8 a00 = *(const bf16x8*)&smem[sA + (abase + (2*(q))    * 16) * 64 + gcx0]; \
      bf16x8 a01 = *(const bf16x8*)&smem[sA + (abase + (2*(q))    * 16) * 64 + gcx1]; \
      bf16x8 a10 = *(const bf16x8*)&smem[sA + (abase + (2*(q)+1)  * 16) * 64 + gcx0]; \
      bf16x8 a11 = *(const bf16x8*)&smem[sA + (abase + (2*(q)+1)  * 16) * 64 + gcx1]; \
      if (more) { STGSTMT; }                                                  \
      __builtin_amdgcn_s_setprio(1);                                          \
      _Pragma("unroll")                                                       \
      for (int n = 0; n < 4; n++) {                                           \
        acc[2*(q)][n]   = __builtin_amdgcn_mfma_f32_16x16x32_bf16(a00, bfr[n][0], acc[2*(q)][n], 0, 0, 0);   \
        acc[2*(q)][n]   = __builtin_amdgcn_mfma_f32_16x16x32_bf16(a01, bfr[n][1], acc[2*(q)][n], 0, 0, 0);   \
        acc[2*(q)+1][n] = __builtin_amdgcn_mfma_f32_16x16x32_bf16(a10, bfr[n][0], acc[2*(q)+1][n], 0, 0, 0); \
        acc[2*(q)+1][n] = __builtin_amdgcn_mfma_f32_16x16x32_bf16(a11, bfr[n][1], acc[2*(q)+1][n], 0, 0, 0); \
      }                                                                       \
      __builtin_amdgcn_s_setprio(0);                                          \
      __builtin_amdgcn_sched_barrier(0);                                      \
      __builtin_amdgcn_s_barrier();                                           \
    } while (0)

    PHASE(1, STG(dA, 1, pA10, pA11));
    PHASE(2, STG(dB, 0, pB00, pB01));
    PHASE(3, STG(dB, 1, pB10, pB11));
#undef PHASE
  }
#undef STG

  // ---- epilogue: acc -> smem[256][256] bf16 (column XOR-swizzled by row:
  // cc ^= (rr&7)<<3, bijective on 8-col-aligned groups), then coalesced store.
  {
    const int rb = wr * 128, cb = wc * 64;
#pragma unroll
    for (int n = 0; n < 4; n++) {
      int cc = cb + n * 16 + lrow;
      float bv = bias[(size_t)e * N + panel * 256 + cc];
#pragma unroll
      for (int m = 0; m < 8; m++)
#pragma unroll
        for (int j = 0; j < 4; j++) {
          int rr = rb + m * 16 + kgrp * 4 + j;
          smem[rr * 256 + (cc ^ ((rr & 7) << 3))] = f2bf(gelu_f(acc[m][n][j] + bv));
        }
    }
    __syncthreads();
    const int r = tid >> 5, c8 = (tid & 31) * 8;
    u16* gdst = Hout + (size_t)(lt * 256) * N + (size_t)panel * 256;
#pragma unroll
    for (int it2 = 0; it2 < 16; ++it2) {
      int rr = it2 * 16 + r;
      *(uint4*)(gdst + (size_t)rr * N + c8) =
          *(const uint4*)&smem[rr * 256 + (c8 ^ ((rr & 7) << 3))];
    }
  }
}

// ---------------- GEMM2: 128x128 4-wave BK=32 2-deep dbuf (proven).
// NO atomics: writes bf16 partials Ybuf[gi][Oq]; epilogue reuses the dead
// 32KB LDS as a [128][128] bf16 out-tile for fully coalesced stores.
__global__ __launch_bounds__(256) void moe_gemm2(
    const u16* __restrict__ A, const u16* __restrict__ W,
    const float* __restrict__ bias, u16* __restrict__ Ybuf,
    const int* __restrict__ cnt, const int* __restrict__ seg_tok,
    const float* __restrict__ seg_wgt, int K, int N, int tile_lo)
{
  const int NP = N / 128;               // 6 panels
  const int lid = (int)blockIdx.x + NP * (int)blockIdx.y;
  const int xcd = lid & 7, slot = lid >> 3;
  const int t2 = xcd + 8 * (slot / NP);
  const int panel = slot % NP;

  const int t256 = tile_lo + (t2 >> 1);
  int pfx[16];
  {
    int tot = 0;
#pragma unroll
    for (int s2 = 0; s2 < 16; s2++) { pfx[s2] = tot; tot += (cnt[s2] + 255) >> 8; }
    if (t256 >= tot) return;
  }
  int seg = 0;
#pragma unroll
  for (int s2 = 1; s2 < 16; s2++) if (pfx[s2] <= t256) seg = s2;
  const int e = seg & 7;
  const int segcnt = cnt[seg];
  const int ti = (t256 - pfx[seg]) * 2 + (t2 & 1);
  const int lt = t2;

  // flat 32 KB LDS: As slot b at [b*4096], Bs slot b at [8192 + b*4096]
  __shared__ u16 smem[16384];
  const int tid  = threadIdx.x;
  const int lane = tid & 63;
  const int wid  = tid >> 6;
  const int wr   = wid >> 1, wc = wid & 1;
  const int lrow = lane & 15, kgrp = lane >> 4;
  const int kx   = kgrp ^ ((lrow >> 1) & 3);
  const int n0 = panel * 128;

  f32x4 acc[4][4];
#pragma unroll
  for (int m = 0; m < 4; m++)
#pragma unroll
    for (int n = 0; n < 4; n++) acc[m][n] = (f32x4){0.f, 0.f, 0.f, 0.f};

  const int r0 = tid >> 2;
  const int kc = (((tid & 3) ^ ((tid >> 3) & 3)) * 8);
  const u16* gA0 = A + (size_t)(lt * 128 + r0) * K + kc;
  const u16* gA1 = gA0 + (size_t)64 * K;
  const u16* gB = W + (size_t)e * K * N + (size_t)(n0 + r0) * K + kc;
  const size_t rowskipB = (size_t)64 * K;
  const int lofs = tid * 8;

  auto stage = [&](int b) {
    gload16(gA0, &smem[b * 4096 + lofs]);
    gload16(gA1, &smem[b * 4096 + lofs + 2048]);
    gload16(gB,            &smem[8192 + b * 4096 + lofs]);
    gload16(gB + rowskipB, &smem[8192 + b * 4096 + lofs + 2048]);
    gA0 += 32; gA1 += 32; gB += 32;
  };

  const int NIT = K / 32;
  stage(0);
  for (int it = 0; it < NIT; ++it) {
    const int cur = it & 1;
    if (it + 1 < NIT) {
      stage(cur ^ 1);
      asm volatile("s_waitcnt vmcnt(4)" ::: "memory");
    } else {
      asm volatile("s_waitcnt vmcnt(0)" ::: "memory");
    }
    __builtin_amdgcn_s_barrier();
    __builtin_amdgcn_sched_barrier(0);
    bf16x8 a[4], b[4];
#pragma unroll
    for (int m = 0; m < 4; m++)
      a[m] = *(const bf16x8*)&smem[cur * 4096 + (wr * 64 + m * 16 + lrow) * 32 + kx * 8];
#pragma unroll
    for (int n = 0; n < 4; n++)
      b[n] = *(const bf16x8*)&smem[8192 + cur * 4096 + (wc * 64 + n * 16 + lrow) * 32 + kx * 8];
#pragma unroll
    for (int m = 0; m < 4; m++)
#pragma unroll
      for (int n = 0; n < 4; n++)
        acc[m][n] = __builtin_amdgcn_mfma_f32_16x16x32_bf16(a[m], b[n], acc[m][n], 0, 0, 0);
    __builtin_amdgcn_sched_barrier(0);
    __builtin_amdgcn_s_barrier();
  }

  // ---- epilogue: (acc + b2)*w -> bf16 LDS [128][128], then coalesced store
  {
    const int rbase = wr * 64;
    const int cbase = wc * 64;
    float bv[4];
#pragma unroll
    for (int n = 0; n < 4; n++)
      bv[n] = bias[(size_t)e * N + n0 + cbase + n * 16 + lrow];
#pragma unroll
    for (int m = 0; m < 4; m++)
#pragma unroll
      for (int j = 0; j < 4; j++) {
        int r = rbase + m * 16 + kgrp * 4 + j;
        int i = ti * 128 + r;
        float w = (i < segcnt) ? seg_wgt[(size_t)seg * Mq + i] : 0.f;
#pragma unroll
        for (int n = 0; n < 4; n++) {
          int c = cbase + n * 16 + lrow;
          smem[r * 128 + (c ^ ((r & 7) << 3))] = f2bf((acc[m][n][j] + bv[n]) * w);
        }
      }
    __syncthreads();
    // gi = global padded slot index of row r in this 128-sub-tile
    const size_t gi0 = (size_t)t256 * 256 + (size_t)(t2 & 1) * 128;
    const int r = tid >> 4, c8 = (tid & 15) * 8;
    u16* gdst = Ybuf + gi0 * Oq + n0;
#pragma unroll
    for (int p = 0; p < 8; ++p) {
      int rr = p * 16 + r;
      *(uint4*)(gdst + (size_t)rr * Oq + c8) =
          *(const uint4*)&smem[rr * 128 + (c8 ^ ((rr & 7) << 3))];
    }
  }
}

// ---------------- fused combine + LayerNorm: out = LN(p0 + p1)
__global__ __launch_bounds__(256) void ln2_kernel(
    const u16* __restrict__ Ybuf, const int* __restrict__ cnt,
    const int2* __restrict__ tok_pos, const float* __restrict__ g,
    const float* __restrict__ b, float* __restrict__ out)
{
  int wid = threadIdx.x >> 6, lane = threadIdx.x & 63;
  int token = blockIdx.x * 4 + wid;
  int pfx[16];
  {
    int tot = 0;
#pragma unroll
    for (int s = 0; s < 16; s++) { pfx[s] = tot; tot += (cnt[s] + 255) >> 8; }
  }
  int2 pp = tok_pos[token];
  size_t gi0 = (size_t)pfx[pp.x & 15] * 256 + (pp.x >> 4);
  size_t gi1 = (size_t)pfx[pp.y & 15] * 256 + (pp.y >> 4);
  const u16* r0 = Ybuf + gi0 * Oq;
  const u16* r1 = Ybuf + gi1 * Oq;

  float v[12];
  {
    uint4 w0 = *(const uint4*)(r0 + lane * 8);
    uint4 w1 = *(const uint4*)(r1 + lane * 8);
    uint32_t u0[4] = {w0.x, w0.y, w0.z, w0.w};
    uint32_t u1[4] = {w1.x, w1.y, w1.z, w1.w};
#pragma unroll
    for (int k = 0; k < 4; k++) {
      v[2 * k]     = bf2f((u16)(u0[k] & 0xffff)) + bf2f((u16)(u1[k] & 0xffff));
      v[2 * k + 1] = bf2f((u16)(u0[k] >> 16))    + bf2f((u16)(u1[k] >> 16));
    }
    ushort4 t0 = *(const ushort4*)(r0 + 512 + lane * 4);
    ushort4 t1 = *(const ushort4*)(r1 + 512 + lane * 4);
    v[8]  = bf2f(t0.x) + bf2f(t1.x);
    v[9]  = bf2f(t0.y) + bf2f(t1.y);
    v[10] = bf2f(t0.z) + bf2f(t1.z);
    v[11] = bf2f(t0.w) + bf2f(t1.w);
  }

  float s = 0.f;
#pragma unroll
  for (int i = 0; i < 12; i++) s += v[i];
#pragma unroll
  for (int off = 32; off; off >>= 1) s += __shfl_xor(s, off);
  float mu = s * (1.0f / Oq);
  float q = 0.f;
#pragma unroll
  for (int i = 0; i < 12; i++) { float d = v[i] - mu; q += d * d; }
#pragma unroll
  for (int off = 32; off; off >>= 1) q += __shfl_xor(q, off);
  float inv = rsqrtf(q * (1.0f / Oq) + LN_EPS);

  float* orow = out + (size_t)token * Oq;
  {
    float4 g0 = *(const float4*)(g + lane * 8);
    float4 g1 = *(const float4*)(g + lane * 8 + 4);
    float4 b0 = *(const float4*)(b + lane * 8);
    float4 b1 = *(const float4*)(b + lane * 8 + 4);
    float4 o0, o1;
    o0.x = (v[0] - mu) * inv * g0.x + b0.x;
    o0.y = (v[1] - mu) * inv * g0.y + b0.y;
    o0.z = (v[2] - mu) * inv * g0.z + b0.z;
    o0.w = (v[3] - mu) * inv * g0.w + b0.w;
    o1.x = (v[4] - mu) * inv * g1.x + b1.x;
    o1.y = (v[5] - mu) * inv * g1.y + b1.y;
    o1.z = (v[6] - mu) * inv * g1.z + b1.z;
    o1.w = (v[7] - mu) * inv * g1.w + b1.w;
    *(float4*)(orow + lane * 8) = o0;
    *(float4*)(orow + lane * 8 + 4) = o1;
    float4 g2v = *(const float4*)(g + 512 + lane * 4);
    float4 b2v = *(const float4*)(b + 512 + lane * 4);
    float4 o2;
    o2.x = (v[8]  - mu) * inv * g2v.x + b2v.x;
    o2.y = (v[9]  - mu) * inv * g2v.y + b2v.y;
    o2.z = (v[10] - mu) * inv * g2v.z + b2v.z;
    o2.w = (v[11] - mu) * inv * g2v.w + b2v.w;
    *(float4*)(orow + 512 + lane * 4) = o2;
  }
}

extern "C" void kernel_launch(void* const* d_in, const int* in_sizes, int n_in,
                              void* d_out, int out_size, void* d_ws, size_t ws_size,
                              hipStream_t stream)
{
  const float* x    = (const float*)d_in[0];
  const float* rw   = (const float*)d_in[1];
  const float* rb   = (const float*)d_in[2];
  const float* w1   = (const float*)d_in[3];
  const float* b1   = (const float*)d_in[4];
  const float* w2   = (const float*)d_in[5];
  const float* b2   = (const float*)d_in[6];
  const float* ln_g = (const float*)d_in[7];
  const float* ln_b = (const float*)d_in[8];
  float* out = (float*)d_out;

  char* ws = (char*)d_ws;
  size_t off = 0;
  auto alloc = [&](size_t bytes) {
    void* p = ws + off;
    off += (bytes + 255) & ~(size_t)255;
    return p;
  };
  int*    cnt     = (int*)alloc(16 * 4);
  int*    tok_seg = (int*)alloc((size_t)Mq * 4);
  float2* tok_w   = (float2*)alloc((size_t)Mq * 8);
  int2*   tok_pos = (int2*)alloc((size_t)Mq * 8);
  int*    seg_tok = (int*)alloc((size_t)16 * Mq * 4);
  float*  seg_wgt = (float*)alloc((size_t)16 * Mq * 4);
  u16* Xbf = (u16*)alloc((size_t)Mq * Dq * 2);
  u16* W1T = (u16*)alloc((size_t)Eq * Dq * Hq * 2);
  u16* W2T = (u16*)alloc((size_t)Eq * Hq * Oq * 2);
  u16* Ybuf = (u16*)alloc((size_t)MAX_T256 * 256 * Oq * 2);   // 56.6 MB

  size_t remain = (ws_size > off) ? ws_size - off : 0;
  size_t tile_bytes = (size_t)256 * Hq * 2;   // 1.5 MB per 256-row tile
  long long wt = (long long)(remain / tile_bytes);
  if (wt > MAX_T256) wt = MAX_T256;
  wt &= ~7LL;                 // multiple of 8 for the XCD remap bijection
  if (wt < 8) wt = 8;
  int WT = (int)wt;
  u16* Hbuf = (u16*)alloc((size_t)WT * tile_bytes);

  prep_kernel<<<NB_ROUTER + NB_TRANS, 256, 0, stream>>>(
      x, rw, rb, Xbf, tok_seg, tok_w, cnt, w1, W1T, w2, W2T);
  scatter_build<<<Mq / 256, 256, 0, stream>>>(tok_seg, tok_w, cnt, seg_tok, seg_wgt, tok_pos);

  for (int tl = 0; tl < MAX_T256; tl += WT) {
    int gx = MAX_T256 - tl; if (gx > WT) gx = WT;   // stays multiple of 8
    moe_gemm1<<<dim3(Hq / 256, gx), 512, 0, stream>>>(
        Xbf, W1T, b1, Hbuf, cnt, seg_tok, Dq, Hq, tl);
    moe_gemm2<<<dim3(Oq / 128, 2 * gx), 256, 0, stream>>>(
        Hbuf, W2T, b2, Ybuf, cnt, seg_tok, seg_wgt, Hq, Oq, tl);
  }
  ln2_kernel<<<Mq / 4, 256, 0, stream>>>(Ybuf, cnt, tok_pos, ln_g, ln_b, out);
}

// Round 23
// 605.315 us; speedup vs baseline: 1.0219x; 1.0219x over previous
//
#include <hip/hip_runtime.h>
#include <hip/hip_bf16.h>
#include <stdint.h>

#define Bq  8
#define Sq  2048
#define Dq  768
#define Hq  3072
#define Oq  768
#define Eq  8
#define Mq  (Bq*Sq)            // 16384 tokens
#define LN_EPS 1e-5f
#define MAX_T256 (Mq/128 + 16)      // 144 worst-case padded 256-row tiles
#define NB_ROUTER (Mq/32)           // 512 router blocks
#define NB_TRANS  (2*Eq*576)        // 9216 transpose blocks (64x64 tiles)

typedef unsigned short u16;
typedef __attribute__((ext_vector_type(4))) float f32x4;
typedef __attribute__((ext_vector_type(8))) __bf16 bf16x8;

static __device__ __forceinline__ u16 f2bf(float f) {
  __hip_bfloat16 h = __float2bfloat16(f);
  return __builtin_bit_cast(u16, h);
}
static __device__ __forceinline__ float bf2f(u16 h) {
  uint32_t u = (uint32_t)h << 16;
  return __builtin_bit_cast(float, u);
}

static __device__ __forceinline__ float gelu_f(float x) {
  float u = 0.7978845608028654f * x * (1.0f + 0.044715f * x * x);
  float e = __expf(2.0f * u);
  float t = 1.0f - 2.0f / (e + 1.0f);   // tanh(u), NaN-free
  return 0.5f * x * (1.0f + t);
}

typedef const __attribute__((address_space(1))) void* gas_t;
typedef __attribute__((address_space(3))) void* las_t;
static __device__ __forceinline__ void gload16(const void* g, void* l) {
  __builtin_amdgcn_global_load_lds((gas_t)g, (las_t)l, 16, 0, 0);
}

// ---------------- UNION prep kernel: router+cvt blocks and weight-transpose
// blocks in ONE dispatch so both memory streams overlap.
// blockIdx.x < NB_ROUTER: router path (8 tokens/wave, 24KB rw^T LDS).
// else: 64x64 transpose+cvt tile of w1 (which=0) or w2 (which=1).
__global__ __launch_bounds__(256) void prep_kernel(
    const float* __restrict__ x, const float* __restrict__ rw,
    const float* __restrict__ rb, u16* __restrict__ Xbf,
    int* __restrict__ tok_seg, float2* __restrict__ tok_w,
    int* __restrict__ cnt,
    const float* __restrict__ w1, u16* __restrict__ W1T,
    const float* __restrict__ w2, u16* __restrict__ W2T)
{
  __shared__ float smem_u[6144];        // 24KB: rwT (router) / 64x65 tile
  const int bid = (int)blockIdx.x;

  if (bid < NB_ROUTER) {
    // ------------- router + x->bf16 path
    if (bid == 0 && threadIdx.x < 16) cnt[threadIdx.x] = 0;
    float* rwT = smem_u;
    for (int i = threadIdx.x; i < Eq * Dq; i += 256)
      rwT[(i & 7) * Dq + (i >> 3)] = rw[i];
    __syncthreads();

    int wid = threadIdx.x >> 6;
    int lane = threadIdx.x & 63;

    for (int tt = 0; tt < 8; ++tt) {
      int token = bid * 32 + wid * 8 + tt;
      const float4* xrow = (const float4*)(x + (size_t)token * Dq);
      ushort4* orow = (ushort4*)(Xbf + (size_t)token * Dq);

      float acc[Eq];
#pragma unroll
      for (int e = 0; e < Eq; e++) acc[e] = 0.f;

#pragma unroll
      for (int it = 0; it < Dq / 256; it++) {
        int d4 = it * 64 + lane;
        float4 xv = xrow[d4];
        ushort4 o;
        o.x = f2bf(xv.x); o.y = f2bf(xv.y); o.z = f2bf(xv.z); o.w = f2bf(xv.w);
        orow[d4] = o;
        int d = d4 * 4;
#pragma unroll
        for (int e = 0; e < Eq; e++) {
          float4 wv = *(const float4*)&rwT[e * Dq + d];
          acc[e] += xv.x * wv.x + xv.y * wv.y + xv.z * wv.z + xv.w * wv.w;
        }
      }
#pragma unroll
      for (int e = 0; e < Eq; e++) {
        float v = acc[e];
#pragma unroll
        for (int off = 32; off; off >>= 1) v += __shfl_xor(v, off);
        acc[e] = v;
      }
      if (lane == 0) {
        float v1 = -1e30f, v2 = -1e30f; int i1 = 0, i2 = 0;
#pragma unroll
        for (int e = 0; e < Eq; e++) {
          float v = acc[e] + rb[e];
          if (v > v1)      { v2 = v1; i2 = i1; v1 = v; i1 = e; }
          else if (v > v2) { v2 = v;  i2 = e; }
        }
        float ex = expf(v2 - v1);
        float wa = 1.f / (1.f + ex);
        float wb = ex / (1.f + ex);
        tok_seg[token] = i1 | ((8 + i2) << 8);
        tok_w[token] = make_float2(wa, wb);
      }
    }
  } else {
    // ------------- 64x64 transpose+cvt path
    const int idx = bid - NB_ROUTER;
    const int which = idx / (Eq * 576);
    const int rem = idx % (Eq * 576);
    const int ex = rem / 576;
    const int tidx = rem % 576;
    const int R = which ? Hq : Dq;
    const int C = which ? Oq : Hq;
    const int NC = C / 64;
    const float* in = (which ? w2 : w1) + (size_t)ex * R * C;
    u16* out = (which ? W2T : W1T) + (size_t)ex * R * C;
    const int c0 = (tidx % NC) * 64;
    const int r0 = (tidx / NC) * 64;
#define TILE(rr, cc) smem_u[(rr) * 65 + (cc)]
    const int fx = threadIdx.x & 15, rbk = threadIdx.x >> 4;   // rbk 0..15
#pragma unroll
    for (int rr = 0; rr < 64; rr += 16) {
      float4 v = *(const float4*)&in[(size_t)(r0 + rr + rbk) * C + c0 + fx * 4];
      TILE(rr + rbk, fx * 4 + 0) = v.x;
      TILE(rr + rbk, fx * 4 + 1) = v.y;
      TILE(rr + rbk, fx * 4 + 2) = v.z;
      TILE(rr + rbk, fx * 4 + 3) = v.w;
    }
    __syncthreads();
    const int j = threadIdx.x & 7;        // 8 lanes per out-row
#pragma unroll
    for (int pass = 0; pass < 2; ++pass) {
      int oc = (threadIdx.x >> 3) + pass * 32;
      u16 vals[8];
#pragma unroll
      for (int k = 0; k < 8; ++k) vals[k] = f2bf(TILE(j * 8 + k, oc));
      uint4 w;
      w.x = vals[0] | ((uint32_t)vals[1] << 16);
      w.y = vals[2] | ((uint32_t)vals[3] << 16);
      w.z = vals[4] | ((uint32_t)vals[5] << 16);
      w.w = vals[6] | ((uint32_t)vals[7] << 16);
      *(uint4*)&out[(size_t)(c0 + oc) * R + r0 + j * 8] = w;
    }
#undef TILE
  }
}

// ---------------- segment-list build, block-aggregated atomics.
// Also records each token's (seg,pos) handle pair for the combine-LN.
__global__ __launch_bounds__(256) void scatter_build(
    const int* __restrict__ tok_seg, const float2* __restrict__ tok_w,
    int* __restrict__ cnt, int* __restrict__ seg_tok, float* __restrict__ seg_wgt,
    int2* __restrict__ tok_pos)
{
  __shared__ int histA[16], histB[16], base[16];
  int t = threadIdx.x;
  if (t < 16) { histA[t] = 0; histB[t] = 0; }
  __syncthreads();
  int token = blockIdx.x * 256 + t;
  int sp = tok_seg[token];
  float2 wv = tok_w[token];
  int s0 = sp & 0xff, s1 = sp >> 8;
  atomicAdd(&histA[s0], 1);
  atomicAdd(&histA[s1], 1);
  __syncthreads();
  if (t < 16) base[t] = atomicAdd(&cnt[t], histA[t]);
  __syncthreads();
  int p0 = base[s0] + atomicAdd(&histB[s0], 1);
  seg_tok[(size_t)s0 * Mq + p0] = token;
  seg_wgt[(size_t)s0 * Mq + p0] = wv.x;
  int p1 = base[s1] + atomicAdd(&histB[s1], 1);
  seg_tok[(size_t)s1 * Mq + p1] = token;
  seg_wgt[(size_t)s1 * Mq + p1] = wv.y;
  tok_pos[token] = make_int2(s0 | (p0 << 4), s1 | (p1 << 4));
}

// ---------------- GEMM1: 256x256 tile, 8 waves (2Mx4N), BK=64, phase-
// pipelined K-loop; LDS 128KB flat smem; coalesced LDS-staged epilogue.
__global__ __launch_bounds__(512, 2) void moe_gemm1(
    const u16* __restrict__ A, const u16* __restrict__ W,
    const float* __restrict__ bias, u16* __restrict__ Hout,
    const int* __restrict__ cnt, const int* __restrict__ seg_tok,
    int K, int N, int tile_lo)
{
  const int NP = N / 256;               // 12 panels
  const int lid = (int)blockIdx.x + NP * (int)blockIdx.y;
  const int xcd = lid & 7, slot = lid >> 3;
  const int t_loc = xcd + 8 * (slot / NP);   // gridDim.y multiple of 8
  const int panel = slot % NP;

  const int t = tile_lo + t_loc;
  int pfx[16];
  {
    int tot = 0;
#pragma unroll
    for (int s2 = 0; s2 < 16; s2++) { pfx[s2] = tot; tot += (cnt[s2] + 255) >> 8; }
    if (t >= tot) return;
  }
  int seg = 0;
#pragma unroll
  for (int s2 = 1; s2 < 16; s2++) if (pfx[s2] <= t) seg = s2;
  const int e = seg & 7;
  const int segcnt = cnt[seg];
  const int ti = t - pfx[seg];
  const int lt = t_loc;

  __shared__ u16 smem[65536];           // 128 KB
  const int tid  = threadIdx.x;
  const int lane = tid & 63;
  const int wid  = tid >> 6;
  const int wr   = wid >> 2, wc = wid & 3;    // 2M x 4N waves
  const int lrow = lane & 15, kgrp = lane >> 4;
  const int gcx0 = ((kgrp)     ^ (lrow & 7)) * 8;
  const int gcx1 = ((4 + kgrp) ^ (lrow & 7)) * 8;

  f32x4 acc[8][4];
#pragma unroll
  for (int m = 0; m < 8; m++)
#pragma unroll
    for (int n = 0; n < 4; n++) acc[m][n] = (f32x4){0.f, 0.f, 0.f, 0.f};

  const int srow = tid >> 3;
  const int swz  = ((tid & 7) ^ (srow & 7)) * 8;
  const u16 *pA00, *pA01, *pA10, *pA11, *pB00, *pB01, *pB10, *pB11;
  {
    int sr;
    sr = ti * 256 +   0 +  0 + srow;
    pA00 = A + (size_t)((sr < segcnt) ? seg_tok[(size_t)seg * Mq + sr] : 0) * K + swz;
    sr = ti * 256 +   0 + 64 + srow;
    pA01 = A + (size_t)((sr < segcnt) ? seg_tok[(size_t)seg * Mq + sr] : 0) * K + swz;
    sr = ti * 256 + 128 +  0 + srow;
    pA10 = A + (size_t)((sr < segcnt) ? seg_tok[(size_t)seg * Mq + sr] : 0) * K + swz;
    sr = ti * 256 + 128 + 64 + srow;
    pA11 = A + (size_t)((sr < segcnt) ? seg_tok[(size_t)seg * Mq + sr] : 0) * K + swz;
    const u16* Wb = W + (size_t)e * K * N;
    pB00 = Wb + (size_t)(panel * 256 +   0 +  0 + srow) * K + swz;
    pB01 = Wb + (size_t)(panel * 256 +   0 + 64 + srow) * K + swz;
    pB10 = Wb + (size_t)(panel * 256 + 128 +  0 + srow) * K + swz;
    pB11 = Wb + (size_t)(panel * 256 + 128 + 64 + srow) * K + swz;
  }

#define STG(base, h, P0, P1)                               \
  do {                                                     \
    gload16(P0, &smem[(base) + (h) * 8192 + tid * 8]);     \
    gload16(P1, &smem[(base) + (h) * 8192 + 4096 + tid * 8]); \
    P0 += 64; P1 += 64;                                    \
  } while (0)

  const int NKT = K / 64;               // 12 K-tiles
  STG(0, 0, pA00, pA01); STG(0, 1, pA10, pA11);
  STG(32768, 0, pB00, pB01); STG(32768, 1, pB10, pB11);

  bf16x8 bfr[4][2];
  for (int kt = 0; kt < NKT; ++kt) {
    const int s = kt & 1;
    const int sA = s * 16384, sB = 32768 + s * 16384;
    const int dA = (s ^ 1) * 16384, dB = 32768 + (s ^ 1) * 16384;
    const bool more = (kt + 1 < NKT);
    const int abase = wr * 128 + lrow;
    const int bbase = wc * 64 + lrow;

    // ---- phase 0
    if (more) {
      STG(dA, 0, pA00, pA01);
      asm volatile("s_waitcnt vmcnt(2)" ::: "memory");
    } else {
      asm volatile("s_waitcnt vmcnt(0)" ::: "memory");
    }
    __builtin_amdgcn_s_barrier();
    __builtin_amdgcn_sched_barrier(0);
#pragma unroll
    for (int n = 0; n < 4; n++) {
      bfr[n][0] = *(const bf16x8*)&smem[sB + (bbase + n * 16) * 64 + gcx0];
      bfr[n][1] = *(const bf16x8*)&smem[sB + (bbase + n * 16) * 64 + gcx1];
    }
    {
      bf16x8 a00 = *(const bf16x8*)&smem[sA + (abase +  0) * 64 + gcx0];
      bf16x8 a01 = *(const bf16x8*)&smem[sA + (abase +  0) * 64 + gcx1];
      bf16x8 a10 = *(const bf16x8*)&smem[sA + (abase + 16) * 64 + gcx0];
      bf16x8 a11 = *(const bf16x8*)&smem[sA + (abase + 16) * 64 + gcx1];
      __builtin_amdgcn_s_setprio(1);
#pragma unroll
      for (int n = 0; n < 4; n++) {
        acc[0][n] = __builtin_amdgcn_mfma_f32_16x16x32_bf16(a00, bfr[n][0], acc[0][n], 0, 0, 0);
        acc[0][n] = __builtin_amdgcn_mfma_f32_16x16x32_bf16(a01, bfr[n][1], acc[0][n], 0, 0, 0);
        acc[1][n] = __builtin_amdgcn_mfma_f32_16x16x32_bf16(a10, bfr[n][0], acc[1][n], 0, 0, 0);
        acc[1][n] = __builtin_amdgcn_mfma_f32_16x16x32_bf16(a11, bfr[n][1], acc[1][n], 0, 0, 0);
      }
      __builtin_amdgcn_s_setprio(0);
    }
    __builtin_amdgcn_sched_barrier(0);
    __builtin_amdgcn_s_barrier();

#define PHASE(q, STGSTMT)                                                     \
    do {                                                                      \
      bf16x8 a00 = *(const bf16x8*)&smem[sA + (abase + (2*(q))    * 16) * 64 + gcx0]; \
      bf16x8 a01 = *(const bf16x8*)&smem[sA + (abase + (2*(q))    * 16) * 64 + gcx1]; \
      bf16x8 a10 = *(const bf16x8*)&smem[sA + (abase + (2*(q)+1)  * 16) * 64 + gcx0]; \
      bf16x8 a11 = *(const bf16x8*)&smem[sA + (abase + (2*(q)+1)  * 16) * 64 + gcx1]; \
      if (more) { STGSTMT; }                                                  \
      __builtin_amdgcn_s_setprio(1);                                          \
      _Pragma("unroll")                                                       \
      for (int n = 0; n < 4; n++) {                                           \
        acc[2*(q)][n]   = __builtin_amdgcn_mfma_f32_16x16x32_bf16(a00, bfr[n][0], acc[2*(q)][n], 0, 0, 0);   \
        acc[2*(q)][n]   = __builtin_amdgcn_mfma_f32_16x16x32_bf16(a01, bfr[n][1], acc[2*(q)][n], 0, 0, 0);   \
        acc[2*(q)+1][n] = __builtin_amdgcn_mfma_f32_16x16x32_bf16(a10, bfr[n][0], acc[2*(q)+1][n], 0, 0, 0); \
        acc[2*(q)+1][n] = __builtin_amdgcn_mfma_f32_16x16x32_bf16(a11, bfr[n][1], acc[2*(q)+1][n], 0, 0, 0); \
      }                                                                       \
      __builtin_amdgcn_s_setprio(0);                                          \
      __builtin_amdgcn_sched_barrier(0);                                      \
      __builtin_amdgcn_s_barrier();                                           \
    } while (0)

    PHASE(1, STG(dA, 1, pA10, pA11));
    PHASE(2, STG(dB, 0, pB00, pB01));
    PHASE(3, STG(dB, 1, pB10, pB11));
#undef PHASE
  }
#undef STG

  // ---- epilogue: scatter acc -> smem[256][256] bf16, then coalesced store
  {
    const int rb = wr * 128, cb = wc * 64;
#pragma unroll
    for (int n = 0; n < 4; n++) {
      int cc = cb + n * 16 + lrow;
      float bv = bias[(size_t)e * N + panel * 256 + cc];
#pragma unroll
      for (int m = 0; m < 8; m++)
#pragma unroll
        for (int j = 0; j < 4; j++) {
          int rr = rb + m * 16 + kgrp * 4 + j;
          smem[rr * 256 + cc] = f2bf(gelu_f(acc[m][n][j] + bv));
        }
    }
    __syncthreads();
    const int r = tid >> 5, c8 = (tid & 31) * 8;
    u16* gdst = Hout + (size_t)(lt * 256) * N + (size_t)panel * 256;
#pragma unroll
    for (int it2 = 0; it2 < 16; ++it2) {
      int rr = it2 * 16 + r;
      *(uint4*)(gdst + (size_t)rr * N + c8) = *(const uint4*)&smem[rr * 256 + c8];
    }
  }
}

// ---------------- GEMM2: 128x128 4-wave BK=32 2-deep dbuf (proven).
// NO atomics: writes bf16 partials Ybuf[gi][Oq]; epilogue reuses the dead
// 32KB LDS as a [128][128] bf16 out-tile for fully coalesced stores.
__global__ __launch_bounds__(256) void moe_gemm2(
    const u16* __restrict__ A, const u16* __restrict__ W,
    const float* __restrict__ bias, u16* __restrict__ Ybuf,
    const int* __restrict__ cnt, const int* __restrict__ seg_tok,
    const float* __restrict__ seg_wgt, int K, int N, int tile_lo)
{
  const int NP = N / 128;               // 6 panels
  const int lid = (int)blockIdx.x + NP * (int)blockIdx.y;
  const int xcd = lid & 7, slot = lid >> 3;
  const int t2 = xcd + 8 * (slot / NP);
  const int panel = slot % NP;

  const int t256 = tile_lo + (t2 >> 1);
  int pfx[16];
  {
    int tot = 0;
#pragma unroll
    for (int s2 = 0; s2 < 16; s2++) { pfx[s2] = tot; tot += (cnt[s2] + 255) >> 8; }
    if (t256 >= tot) return;
  }
  int seg = 0;
#pragma unroll
  for (int s2 = 1; s2 < 16; s2++) if (pfx[s2] <= t256) seg = s2;
  const int e = seg & 7;
  const int segcnt = cnt[seg];
  const int ti = (t256 - pfx[seg]) * 2 + (t2 & 1);
  const int lt = t2;

  // flat 32 KB LDS: As slot b at [b*4096], Bs slot b at [8192 + b*4096]
  __shared__ u16 smem[16384];
  const int tid  = threadIdx.x;
  const int lane = tid & 63;
  const int wid  = tid >> 6;
  const int wr   = wid >> 1, wc = wid & 1;
  const int lrow = lane & 15, kgrp = lane >> 4;
  const int kx   = kgrp ^ ((lrow >> 1) & 3);
  const int n0 = panel * 128;

  f32x4 acc[4][4];
#pragma unroll
  for (int m = 0; m < 4; m++)
#pragma unroll
    for (int n = 0; n < 4; n++) acc[m][n] = (f32x4){0.f, 0.f, 0.f, 0.f};

  const int r0 = tid >> 2;
  const int kc = (((tid & 3) ^ ((tid >> 3) & 3)) * 8);
  const u16* gA0 = A + (size_t)(lt * 128 + r0) * K + kc;
  const u16* gA1 = gA0 + (size_t)64 * K;
  const u16* gB = W + (size_t)e * K * N + (size_t)(n0 + r0) * K + kc;
  const size_t rowskipB = (size_t)64 * K;
  const int lofs = tid * 8;

  auto stage = [&](int b) {
    gload16(gA0, &smem[b * 4096 + lofs]);
    gload16(gA1, &smem[b * 4096 + lofs + 2048]);
    gload16(gB,            &smem[8192 + b * 4096 + lofs]);
    gload16(gB + rowskipB, &smem[8192 + b * 4096 + lofs + 2048]);
    gA0 += 32; gA1 += 32; gB += 32;
  };

  const int NIT = K / 32;
  stage(0);
  for (int it = 0; it < NIT; ++it) {
    const int cur = it & 1;
    if (it + 1 < NIT) {
      stage(cur ^ 1);
      asm volatile("s_waitcnt vmcnt(4)" ::: "memory");
    } else {
      asm volatile("s_waitcnt vmcnt(0)" ::: "memory");
    }
    __builtin_amdgcn_s_barrier();
    __builtin_amdgcn_sched_barrier(0);
    bf16x8 a[4], b[4];
#pragma unroll
    for (int m = 0; m < 4; m++)
      a[m] = *(const bf16x8*)&smem[cur * 4096 + (wr * 64 + m * 16 + lrow) * 32 + kx * 8];
#pragma unroll
    for (int n = 0; n < 4; n++)
      b[n] = *(const bf16x8*)&smem[8192 + cur * 4096 + (wc * 64 + n * 16 + lrow) * 32 + kx * 8];
#pragma unroll
    for (int m = 0; m < 4; m++)
#pragma unroll
      for (int n = 0; n < 4; n++)
        acc[m][n] = __builtin_amdgcn_mfma_f32_16x16x32_bf16(a[m], b[n], acc[m][n], 0, 0, 0);
    __builtin_amdgcn_sched_barrier(0);
    __builtin_amdgcn_s_barrier();
  }

  // ---- epilogue: (acc + b2)*w -> bf16 LDS [128][128], then coalesced store
  {
    const int rbase = wr * 64;
    const int cbase = wc * 64;
    float bv[4];
#pragma unroll
    for (int n = 0; n < 4; n++)
      bv[n] = bias[(size_t)e * N + n0 + cbase + n * 16 + lrow];
#pragma unroll
    for (int m = 0; m < 4; m++)
#pragma unroll
      for (int j = 0; j < 4; j++) {
        int r = rbase + m * 16 + kgrp * 4 + j;
        int i = ti * 128 + r;
        float w = (i < segcnt) ? seg_wgt[(size_t)seg * Mq + i] : 0.f;
#pragma unroll
        for (int n = 0; n < 4; n++) {
          int c = cbase + n * 16 + lrow;
          smem[r * 128 + c] = f2bf((acc[m][n][j] + bv[n]) * w);
        }
      }
    __syncthreads();
    // gi = global padded slot index of row r in this 128-sub-tile
    const size_t gi0 = (size_t)t256 * 256 + (size_t)(t2 & 1) * 128;
    const int r = tid >> 4, c8 = (tid & 15) * 8;
    u16* gdst = Ybuf + gi0 * Oq + n0;
#pragma unroll
    for (int p = 0; p < 8; ++p) {
      int rr = p * 16 + r;
      *(uint4*)(gdst + (size_t)rr * Oq + c8) = *(const uint4*)&smem[rr * 128 + c8];
    }
  }
}

// ---------------- fused combine + LayerNorm: out = LN(p0 + p1)
__global__ __launch_bounds__(256) void ln2_kernel(
    const u16* __restrict__ Ybuf, const int* __restrict__ cnt,
    const int2* __restrict__ tok_pos, const float* __restrict__ g,
    const float* __restrict__ b, float* __restrict__ out)
{
  int wid = threadIdx.x >> 6, lane = threadIdx.x & 63;
  int token = blockIdx.x * 4 + wid;
  int pfx[16];
  {
    int tot = 0;
#pragma unroll
    for (int s = 0; s < 16; s++) { pfx[s] = tot; tot += (cnt[s] + 255) >> 8; }
  }
  int2 pp = tok_pos[token];
  size_t gi0 = (size_t)pfx[pp.x & 15] * 256 + (pp.x >> 4);
  size_t gi1 = (size_t)pfx[pp.y & 15] * 256 + (pp.y >> 4);
  const u16* r0 = Ybuf + gi0 * Oq;
  const u16* r1 = Ybuf + gi1 * Oq;

  float v[12];
  {
    uint4 w0 = *(const uint4*)(r0 + lane * 8);
    uint4 w1 = *(const uint4*)(r1 + lane * 8);
    uint32_t u0[4] = {w0.x, w0.y, w0.z, w0.w};
    uint32_t u1[4] = {w1.x, w1.y, w1.z, w1.w};
#pragma unroll
    for (int k = 0; k < 4; k++) {
      v[2 * k]     = bf2f((u16)(u0[k] & 0xffff)) + bf2f((u16)(u1[k] & 0xffff));
      v[2 * k + 1] = bf2f((u16)(u0[k] >> 16))    + bf2f((u16)(u1[k] >> 16));
    }
    ushort4 t0 = *(const ushort4*)(r0 + 512 + lane * 4);
    ushort4 t1 = *(const ushort4*)(r1 + 512 + lane * 4);
    v[8]  = bf2f(t0.x) + bf2f(t1.x);
    v[9]  = bf2f(t0.y) + bf2f(t1.y);
    v[10] = bf2f(t0.z) + bf2f(t1.z);
    v[11] = bf2f(t0.w) + bf2f(t1.w);
  }

  float s = 0.f;
#pragma unroll
  for (int i = 0; i < 12; i++) s += v[i];
#pragma unroll
  for (int off = 32; off; off >>= 1) s += __shfl_xor(s, off);
  float mu = s * (1.0f / Oq);
  float q = 0.f;
#pragma unroll
  for (int i = 0; i < 12; i++) { float d = v[i] - mu; q += d * d; }
#pragma unroll
  for (int off = 32; off; off >>= 1) q += __shfl_xor(q, off);
  float inv = rsqrtf(q * (1.0f / Oq) + LN_EPS);

  float* orow = out + (size_t)token * Oq;
  {
    float4 g0 = *(const float4*)(g + lane * 8);
    float4 g1 = *(const float4*)(g + lane * 8 + 4);
    float4 b0 = *(const float4*)(b + lane * 8);
    float4 b1 = *(const float4*)(b + lane * 8 + 4);
    float4 o0, o1;
    o0.x = (v[0] - mu) * inv * g0.x + b0.x;
    o0.y = (v[1] - mu) * inv * g0.y + b0.y;
    o0.z = (v[2] - mu) * inv * g0.z + b0.z;
    o0.w = (v[3] - mu) * inv * g0.w + b0.w;
    o1.x = (v[4] - mu) * inv * g1.x + b1.x;
    o1.y = (v[5] - mu) * inv * g1.y + b1.y;
    o1.z = (v[6] - mu) * inv * g1.z + b1.z;
    o1.w = (v[7] - mu) * inv * g1.w + b1.w;
    *(float4*)(orow + lane * 8) = o0;
    *(float4*)(orow + lane * 8 + 4) = o1;
    float4 g2v = *(const float4*)(g + 512 + lane * 4);
    float4 b2v = *(const float4*)(b + 512 + lane * 4);
    float4 o2;
    o2.x = (v[8]  - mu) * inv * g2v.x + b2v.x;
    o2.y = (v[9]  - mu) * inv * g2v.y + b2v.y;
    o2.z = (v[10] - mu) * inv * g2v.z + b2v.z;
    o2.w = (v[11] - mu) * inv * g2v.w + b2v.w;
    *(float4*)(orow + 512 + lane * 4) = o2;
  }
}

extern "C" void kernel_launch(void* const* d_in, const int* in_sizes, int n_in,
                              void* d_out, int out_size, void* d_ws, size_t ws_size,
                              hipStream_t stream)
{
  const float* x    = (const float*)d_in[0];
  const float* rw   = (const float*)d_in[1];
  const float* rb   = (const float*)d_in[2];
  const float* w1   = (const float*)d_in[3];
  const float* b1   = (const float*)d_in[4];
  const float* w2   = (const float*)d_in[5];
  const float* b2   = (const float*)d_in[6];
  const float* ln_g = (const float*)d_in[7];
  const float* ln_b = (const float*)d_in[8];
  float* out = (float*)d_out;

  char* ws = (char*)d_ws;
  size_t off = 0;
  auto alloc = [&](size_t bytes) {
    void* p = ws + off;
    off += (bytes + 255) & ~(size_t)255;
    return p;
  };
  int*    cnt     = (int*)alloc(16 * 4);
  int*    tok_seg = (int*)alloc((size_t)Mq * 4);
  float2* tok_w   = (float2*)alloc((size_t)Mq * 8);
  int2*   tok_pos = (int2*)alloc((size_t)Mq * 8);
  int*    seg_tok = (int*)alloc((size_t)16 * Mq * 4);
  float*  seg_wgt = (float*)alloc((size_t)16 * Mq * 4);
  u16* Xbf = (u16*)alloc((size_t)Mq * Dq * 2);
  u16* W1T = (u16*)alloc((size_t)Eq * Dq * Hq * 2);
  u16* W2T = (u16*)alloc((size_t)Eq * Hq * Oq * 2);
  u16* Ybuf = (u16*)alloc((size_t)MAX_T256 * 256 * Oq * 2);   // 56.6 MB

  size_t remain = (ws_size > off) ? ws_size - off : 0;
  size_t tile_bytes = (size_t)256 * Hq * 2;   // 1.5 MB per 256-row tile
  long long wt = (long long)(remain / tile_bytes);
  if (wt > MAX_T256) wt = MAX_T256;
  wt &= ~7LL;                 // multiple of 8 for the XCD remap bijection
  if (wt < 8) wt = 8;
  int WT = (int)wt;
  u16* Hbuf = (u16*)alloc((size_t)WT * tile_bytes);

  prep_kernel<<<NB_ROUTER + NB_TRANS, 256, 0, stream>>>(
      x, rw, rb, Xbf, tok_seg, tok_w, cnt, w1, W1T, w2, W2T);
  scatter_build<<<Mq / 256, 256, 0, stream>>>(tok_seg, tok_w, cnt, seg_tok, seg_wgt, tok_pos);

  for (int tl = 0; tl < MAX_T256; tl += WT) {
    int gx = MAX_T256 - tl; if (gx > WT) gx = WT;   // stays multiple of 8
    moe_gemm1<<<dim3(Hq / 256, gx), 512, 0, stream>>>(
        Xbf, W1T, b1, Hbuf, cnt, seg_tok, Dq, Hq, tl);
    moe_gemm2<<<dim3(Oq / 128, 2 * gx), 256, 0, stream>>>(
        Hbuf, W2T, b2, Ybuf, cnt, seg_tok, seg_wgt, Hq, Oq, tl);
  }
  ln2_kernel<<<Mq / 4, 256, 0, stream>>>(Ybuf, cnt, tok_pos, ln_g, ln_b, out);
}